// Round 1
// 68.070 us; speedup vs baseline: 1.0480x; 1.0480x over previous
//
#include <hip/hip_runtime.h>

#define M 512           // points per cluster
#define K 64            // clusters
#define TP 64           // tile edge (points)
#define NT 256          // threads per block (4 waves)
#define NTILES 36       // tile-pairs a<=b of the 8x8 tile grid

// The 36 tile-pairs (a<=b) of the 8x8 tile grid.
__device__ __constant__ unsigned char TA_tab[36] = {
    0,0,0,0,0,0,0,0, 1,1,1,1,1,1,1, 2,2,2,2,2,2, 3,3,3,3,3, 4,4,4,4, 5,5,5, 6,6, 7};
__device__ __constant__ unsigned char TB_tab[36] = {
    0,1,2,3,4,5,6,7, 1,2,3,4,5,6,7, 2,3,4,5,6,7, 3,4,5,6,7, 4,5,6,7, 5,6,7, 6,7, 7};

// One tile-pair per block: grid = K*NTILES = 2304 blocks (~9 blocks/CU,
// ~8-9 waves/SIMD vs 2.25 before) so LDS-broadcast and staging latency is
// hidden by TLP. Staging is now only the two 64-point tiles this block
// touches (384 floats vs 3072), so the serial prologue shrinks 8x.
// Coordinates pre-scaled by 1/d_thre: per-pair term = min((ds-dt)^2, 1).
// Symmetry: off-diagonal tile-pairs doubled; per-block partial goes to d_ws,
// a tiny second kernel reduces 2304 partials and STORES the result
// (no same-address atomic contention, no dependence on d_out poison value).
__global__ __launch_bounds__(NT) void sc_tile_kernel(
    const float* __restrict__ flow,
    const float* __restrict__ pc1,
    float* __restrict__ part)
{
    // Point-major padded layout: [pt][0..2]=src*inv_d, [pt][4..6]=tgt*inv_d.
    // Rows 0..63 = tile a (rows), rows 64..127 = tile b (columns).
    // 32B row stride -> float4 reads are ds_read_b128; row reads broadcast.
    __shared__ __align__(16) float Pl[2 * TP][8];
    __shared__ float wsum[NT / 64];

    const int blk = blockIdx.x;
    const int c   = blk / NTILES;          // cluster
    const int p   = blk - c * NTILES;      // tile-pair index (block-uniform)
    const int a   = TA_tab[p];
    const int b   = TB_tab[p];
    const int tid = threadIdx.x;

    const float inv_d = 1.0f / 0.03f;
    const int base = c * (M * 3);

    // Stage the two tiles: 128 points x 3 comps = 384 elements.
#pragma unroll
    for (int it = 0; it < 2; ++it) {
        const int idx = tid + it * NT;
        if (idx < 6 * TP) {
            const int pt   = idx / 3;              // 0..127
            const int comp = idx - pt * 3;
            const int spt  = (pt < TP) ? (a * TP + pt) : (b * TP + (pt - TP));
            const int g    = base + spt * 3 + comp;
            const float pv = pc1[g];
            const float fv = flow[g];
            Pl[pt][comp]     = pv * inv_d;
            Pl[pt][comp + 4] = (pv + fv) * inv_d;
        }
    }
    __syncthreads();

    const int lane = tid & 63;             // column within tile b
    const int wave = tid >> 6;             // 4 waves x 16 rows of tile a

    const float4 cs = *(const float4*)&Pl[TP + lane][0];
    const float4 ct = *(const float4*)&Pl[TP + lane][4];

    float acc = 0.0f;
    const int r0 = wave * (TP / 4);
#pragma unroll
    for (int rr = 0; rr < TP / 4; ++rr) {
        // all-lane broadcast LDS reads (conflict-free)
        const float4 rs = *(const float4*)&Pl[r0 + rr][0];
        const float4 rt = *(const float4*)&Pl[r0 + rr][4];

        const float dx = rs.x - cs.x, dy = rs.y - cs.y, dz = rs.z - cs.z;
        const float ds = __builtin_amdgcn_sqrtf(dx * dx + dy * dy + dz * dz);
        const float ex = rt.x - ct.x, ey = rt.y - ct.y, ez = rt.z - ct.z;
        const float dt = __builtin_amdgcn_sqrtf(ex * ex + ey * ey + ez * ez);
        // min(diff^2, 1) == min(|diff|, 1)^2 ; abs is a free VOP3 modifier
        const float m = fminf(fabsf(ds - dt), 1.0f);
        acc = fmaf(m, m, acc);
    }
    if (a != b) acc += acc;                // off-diagonal tiles count twice

    // Wave reduction, then cross-wave via LDS, one store per block.
    for (int off = 32; off > 0; off >>= 1)
        acc += __shfl_down(acc, off, 64);
    if (lane == 0) wsum[wave] = acc;
    __syncthreads();
    if (tid == 0)
        part[blk] = wsum[0] + wsum[1] + wsum[2] + wsum[3];
}

// Final reduction: 2304 partials -> single store (overwrites d_out poison).
__global__ __launch_bounds__(NT) void sc_reduce_kernel(
    const float* __restrict__ part,
    float* __restrict__ out)
{
    __shared__ float wsum[NT / 64];
    float s = 0.0f;
#pragma unroll
    for (int i = 0; i < (K * NTILES) / NT; ++i)   // 9 iterations
        s += part[threadIdx.x + i * NT];
    for (int off = 32; off > 0; off >>= 1)
        s += __shfl_down(s, off, 64);
    const int lane = threadIdx.x & 63;
    const int wave = threadIdx.x >> 6;
    if (lane == 0) wsum[wave] = s;
    __syncthreads();
    if (threadIdx.x == 0)
        out[0] = (wsum[0] + wsum[1] + wsum[2] + wsum[3]) * (1.0f / 16777216.0f);
}

extern "C" void kernel_launch(void* const* d_in, const int* in_sizes, int n_in,
                              void* d_out, int out_size, void* d_ws, size_t ws_size,
                              hipStream_t stream)
{
    const float* flow = (const float*)d_in[0];
    const float* pc1  = (const float*)d_in[1];
    float* out  = (float*)d_out;
    float* part = (float*)d_ws;            // K*NTILES*4 = 9216 B << ws_size

    sc_tile_kernel<<<K * NTILES, NT, 0, stream>>>(flow, pc1, part);
    sc_reduce_kernel<<<1, NT, 0, stream>>>(part, out);
}